// Round 1
// baseline (117.728 us; speedup 1.0000x reference)
//
#include <hip/hip_runtime.h>
#include <math.h>

#define NC 15

__device__ __forceinline__ float bce_f(float x, float t) {
    return fmaxf(x, 0.0f) - x * t + log1pf(expf(-fabsf(x)));
}
__device__ __forceinline__ float sig_f(float x) { return 1.0f / (1.0f + expf(-x)); }
__device__ __forceinline__ float focal_f(float x, float t) {
    float d = t - sig_f(x);
    return bce_f(x, t) * d * d;   // alpha=1, |d|^2.0 == d*d
}
__device__ __forceinline__ float sl1_f(float x, float t) {
    float n = fabsf(x - t);
    return n < 1.0f ? 0.5f * n * n : n - 0.5f;
}

__device__ __forceinline__ float giou_f(const float* b, float lx, float ly, float lw, float lh) {
    float b1x0 = b[0] - b[2] * 0.5f, b1y0 = b[1] - b[3] * 0.5f;
    float b1x1 = b[0] + b[2] * 0.5f, b1y1 = b[1] + b[3] * 0.5f;
    float b2x0 = lx - lw * 0.5f, b2y0 = ly - lh * 0.5f;
    float b2x1 = lx + lw * 0.5f, b2y1 = ly + lh * 0.5f;
    float ax0 = fminf(b1x0, b1x1), ay0 = fminf(b1y0, b1y1);
    float ax1 = fmaxf(b1x0, b1x1), ay1 = fmaxf(b1y0, b1y1);
    float cx0 = fminf(b2x0, b2x1), cy0 = fminf(b2y0, b2y1);
    float cx1 = fmaxf(b2x0, b2x1), cy1 = fmaxf(b2y0, b2y1);
    float a1 = (ax1 - ax0) * (ay1 - ay0);
    float a2 = (cx1 - cx0) * (cy1 - cy0);
    float ltx = fmaxf(ax0, cx0), lty = fmaxf(ay0, cy0);
    float rbx = fminf(ax1, cx1), rby = fminf(ay1, cy1);
    float iw = fmaxf(rbx - ltx, 0.0f), ih = fmaxf(rby - lty, 0.0f);
    float inter = iw * ih;
    float uni = a1 + a2 - inter;
    float iou = inter / (uni + 1e-6f);
    float ex0 = fminf(ax0, cx0), ey0 = fminf(ay0, cy0);
    float ex1 = fmaxf(ax1, cx1), ey1 = fmaxf(ay1, cy1);
    float ew = fmaxf(ex1 - ex0, 0.0f), eh = fmaxf(ey1 - ey0, 0.0f);
    float enc = ew * eh;
    return iou - (enc - uni) / (enc + 1e-6f);
}

__global__ __launch_bounds__(256) void count_kernel(const float* __restrict__ label,
                                                    int batchShift, int nCells,
                                                    unsigned int* __restrict__ counts) {
    __shared__ unsigned int sc[16];
    if (threadIdx.x < 16) sc[threadIdx.x] = 0u;
    __syncthreads();
    int i = blockIdx.x * 256 + threadIdx.x;
    if (i < nCells) {
        float flag = label[(size_t)i * 31 + 13];
        if (flag == 1.0f) atomicAdd(&sc[i >> batchShift], 1u);
    }
    __syncthreads();
    if (threadIdx.x < 16 && sc[threadIdx.x] != 0u) atomicAdd(&counts[threadIdx.x], sc[threadIdx.x]);
}

__global__ __launch_bounds__(256) void loss_kernel(
    const float* __restrict__ p1, const float* __restrict__ p1d,
    const float* __restrict__ p2, const float* __restrict__ p2d,
    const float* __restrict__ label,
    const unsigned int* __restrict__ counts,
    double* __restrict__ sums,
    int nCells, int batchShift, float invStride)
{
    int i = blockIdx.x * 256 + threadIdx.x;
    float v[15];
#pragma unroll
    for (int t = 0; t < 15; ++t) v[t] = 0.0f;

    if (i < nCells) {
        const float* lb = label + (size_t)i * 31;
        float lx = lb[0], ly = lb[1], lw = lb[2], lh = lb[3];
        float l1234[4] = {lb[4], lb[5], lb[6], lb[7]};
        float la[4] = {lb[8], lb[9], lb[10], lb[11]};
        float lr = lb[12];
        float flag = lb[13];
        float mix = lb[14];
        float area = lb[15];
        float cls[NC];
#pragma unroll
        for (int k = 0; k < NC; ++k) cls[k] = lb[16 + k];

        float obj   = (flag == 1.0f) ? 1.0f : 0.0f;
        float noobj = (flag == 0.0f) ? 1.0f : 0.0f;
        float fuzzy = 1.0f - obj - noobj;

        float gh = cls[0];
#pragma unroll
        for (int k = 1; k < NC; ++k) gh = fmaxf(gh, cls[k]);

        float conf_t = obj * 0.99f + 0.005f;
        float aw = area + ((area == 0.0f) ? 1.0f : 0.0f);
        float bls = 2.0f - lw * lh * (1.0f / (1024.0f * 1024.0f));

        unsigned int cnt = counts[i >> batchShift];
        float invN = 1.0f / (float)(cnt > 1u ? cnt : 1u);

        // ---------------- head 1 ----------------
        {
            const float* q = p1d + (size_t)i * 13;
            float pd[13];
#pragma unroll
            for (int k = 0; k < 13; ++k) pd[k] = q[k];
            float conf = p1[(size_t)i * 10 + 9];

            float xiou = giou_f(pd, lx, ly, lw, lh);
            float siou = bls * (1.0f - fminf(fmaxf(xiou, 0.0f), 1.0f));
            float sobb = 0.0f;
#pragma unroll
            for (int k = 0; k < 4; ++k) { float d = pd[4 + k] - la[k]; sobb += d * d; }
            float dr = pd[8] - lr;
            float sarea = dr * dr;
            float off = expf(-(siou + sobb + sarea));
            float g = (gh + off) * 0.5f;
            float bg = noobj + fuzzy * ((g < 0.3f) ? 1.0f : 0.0f) * (1.0f - fuzzy * g);
            float fg = obj * ((g >= 0.3f) ? 1.0f : 0.0f);
            float foc = focal_f(conf, conf_t);
            float fma_ = fg * mix * aw;
            v[0] = fg * foc * mix * g;
            v[1] = bg * foc * mix;
            v[2] = fma_ * siou;
            v[3] = fma_ * sobb;
            v[4] = fma_ * sarea;
            float sl = 0.0f;
#pragma unroll
            for (int k = 0; k < 4; ++k) sl += sl1_f(pd[9 + k] * invStride, l1234[k] * invStride);
            v[5] = fg * bls * sl * mix * aw;
        }
        // ---------------- head 2 ----------------
        {
            const float* q = p2d + (size_t)i * 13;
            float pd[13];
#pragma unroll
            for (int k = 0; k < 13; ++k) pd[k] = q[k];
            const float* r2p = p2 + (size_t)i * 25;
            float conf = r2p[9];

            float xiou = giou_f(pd, lx, ly, lw, lh);
            float siou = bls * (1.0f - fminf(fmaxf(xiou, 0.0f), 1.0f));
            float sobb = 0.0f;
#pragma unroll
            for (int k = 0; k < 4; ++k) { float d = pd[4 + k] - la[k]; sobb += d * d; }
            float dr = pd[8] - lr;
            float sarea = dr * dr;
            float off2 = expf(-(siou + sobb + sarea));
            float g = (gh + off2) * 0.5f;
            float bg = noobj + fuzzy * ((g < 0.3f) ? 1.0f : 0.0f) * (1.0f - fuzzy * g);
            float fg = obj * ((g >= 0.3f) ? 1.0f : 0.0f);
            float foc = focal_f(conf, conf_t);
            v[6] = fg * foc * mix * g;
            v[7] = bg * foc * mix;

            float pos = 0.0f, neg = 0.0f, wsum = 0.0f, clsb = 0.0f;
#pragma unroll
            for (int k = 0; k < NC; ++k) {
                float x = r2p[10 + k];
                bool nz = (cls[k] != 0.0f);
                float smn = (nz ? 0.99f : 0.0f) + (0.01f / 15.0f);
                float b0 = bce_f(x, smn);
                clsb += b0;
                if (nz) {
                    pos += bce_f(x, smn * off2);
                    wsum += sig_f(x);
                } else {
                    neg += b0;
                }
            }
            float wgq = (wsum + gh) * 0.5f;
            float oma = obj * mix * aw;
            v[8] = oma * pos;
            v[9] = oma * neg;
            float fmaw = fg * mix * aw * wgq;
            v[10] = fmaw * siou;
            v[12] = fmaw * sobb;
            v[13] = fmaw * sarea;
            float sl = 0.0f;
#pragma unroll
            for (int k = 0; k < 4; ++k) sl += sl1_f(pd[9 + k] * invStride, l1234[k] * invStride);
            v[14] = fg * bls * sl * mix * aw * wgq;
            v[11] = fg * clsb * mix * aw;
        }
#pragma unroll
        for (int t = 0; t < 15; ++t) v[t] *= invN;
    }

    // block reduction: wave shuffle -> LDS -> f64 atomics
    __shared__ float red[4][16];
    int lane = threadIdx.x & 63;
    int wid = threadIdx.x >> 6;
#pragma unroll
    for (int t = 0; t < 15; ++t) {
        float x = v[t];
#pragma unroll
        for (int o = 32; o > 0; o >>= 1) x += __shfl_down(x, o);
        if (lane == 0) red[wid][t] = x;
    }
    __syncthreads();
    if (threadIdx.x < 15) {
        float total = red[0][threadIdx.x] + red[1][threadIdx.x] + red[2][threadIdx.x] + red[3][threadIdx.x];
        atomicAdd(&sums[threadIdx.x], (double)total);
    }
}

__global__ void finalize_kernel(const double* __restrict__ sums, float* __restrict__ out) {
    if (threadIdx.x == 0 && blockIdx.x == 0) {
        const double invB = 1.0 / 16.0;
        double fg  = (sums[0] + sums[6]) * invB;
        double bg  = (sums[1] + sums[7]) * invB;
        double pos = sums[8]  * invB * 28.0;   // *(NC-1)=14, then *2
        double neg = sums[9]  * invB * 2.0;
        double cls = sums[11] * invB;
        double iou = (sums[2] + sums[10]) * invB * 0.5;
        double s   = (sums[3] + sums[12]) * invB * 0.5;
        double r   = (sums[4] + sums[13]) * invB * 8.0;   // 16 * avg-of-2
        double l   = (sums[5] + sums[14]) * invB * 0.1;   // 0.2 * avg-of-2
        double loss = fg + bg + iou + s + r + pos + neg + l;
        out[0] = (float)loss; out[1] = (float)fg; out[2] = (float)bg;
        out[3] = (float)pos;  out[4] = (float)neg; out[5] = (float)iou;
        out[6] = (float)cls;  out[7] = (float)s;   out[8] = (float)r;
        out[9] = (float)l;
    }
}

extern "C" void kernel_launch(void* const* d_in, const int* in_sizes, int n_in,
                              void* d_out, int out_size, void* d_ws, size_t ws_size,
                              hipStream_t stream) {
    (void)in_sizes; (void)n_in; (void)out_size; (void)ws_size;
    unsigned int* counts = (unsigned int*)d_ws;                 // 3 levels * 16 batch
    double* sums = (double*)((char*)d_ws + 256);                // 15 doubles
    hipMemsetAsync(d_ws, 0, 256 + 15 * sizeof(double), stream);

    const int B = 16;
    const int Gs[3] = {128, 64, 32};
    const float strides[3] = {8.0f, 16.0f, 32.0f};
    const int shifts[3] = {14, 12, 10};   // log2(G*G)

    for (int lvl = 0; lvl < 3; ++lvl) {
        const float* label = (const float*)d_in[lvl * 5 + 4];
        int nCells = B * Gs[lvl] * Gs[lvl];
        count_kernel<<<dim3((nCells + 255) / 256), dim3(256), 0, stream>>>(
            label, shifts[lvl], nCells, counts + lvl * 16);
    }
    for (int lvl = 0; lvl < 3; ++lvl) {
        const float* p1    = (const float*)d_in[lvl * 5 + 0];
        const float* p1d   = (const float*)d_in[lvl * 5 + 1];
        const float* p2    = (const float*)d_in[lvl * 5 + 2];
        const float* p2d   = (const float*)d_in[lvl * 5 + 3];
        const float* label = (const float*)d_in[lvl * 5 + 4];
        int nCells = B * Gs[lvl] * Gs[lvl];
        loss_kernel<<<dim3(nCells / 256), dim3(256), 0, stream>>>(
            p1, p1d, p2, p2d, label, counts + lvl * 16, sums,
            nCells, shifts[lvl], 1.0f / strides[lvl]);
    }
    finalize_kernel<<<dim3(1), dim3(64), 0, stream>>>(sums, (float*)d_out);
}

// Round 2
// 64.556 us; speedup vs baseline: 1.8237x; 1.8237x over previous
//
#include <hip/hip_runtime.h>
#include <math.h>

#define NC 15

struct Params {
    const float* p1[3];
    const float* p1d[3];
    const float* p2[3];
    const float* p2d[3];
    const float* lb[3];
    double* sums;   // [3 levels][16 batch][16 terms]
};

__device__ __forceinline__ float bce_f(float x, float t) {
    return fmaxf(x, 0.0f) - x * t + log1pf(expf(-fabsf(x)));
}
__device__ __forceinline__ float sig_f(float x) { return 1.0f / (1.0f + expf(-x)); }
__device__ __forceinline__ float focal_f(float x, float t) {
    float d = t - sig_f(x);
    return bce_f(x, t) * d * d;   // alpha=1, gamma=2 -> |d|^2 == d*d
}
__device__ __forceinline__ float sl1_f(float x, float t) {
    float n = fabsf(x - t);
    return n < 1.0f ? 0.5f * n * n : n - 0.5f;
}

__device__ __forceinline__ float giou_f(const float* b, float lx, float ly, float lw, float lh) {
    float b1x0 = b[0] - b[2] * 0.5f, b1y0 = b[1] - b[3] * 0.5f;
    float b1x1 = b[0] + b[2] * 0.5f, b1y1 = b[1] + b[3] * 0.5f;
    float b2x0 = lx - lw * 0.5f, b2y0 = ly - lh * 0.5f;
    float b2x1 = lx + lw * 0.5f, b2y1 = ly + lh * 0.5f;
    float ax0 = fminf(b1x0, b1x1), ay0 = fminf(b1y0, b1y1);
    float ax1 = fmaxf(b1x0, b1x1), ay1 = fmaxf(b1y0, b1y1);
    float cx0 = fminf(b2x0, b2x1), cy0 = fminf(b2y0, b2y1);
    float cx1 = fmaxf(b2x0, b2x1), cy1 = fmaxf(b2y0, b2y1);
    float a1 = (ax1 - ax0) * (ay1 - ay0);
    float a2 = (cx1 - cx0) * (cy1 - cy0);
    float ltx = fmaxf(ax0, cx0), lty = fmaxf(ay0, cy0);
    float rbx = fminf(ax1, cx1), rby = fminf(ay1, cy1);
    float iw = fmaxf(rbx - ltx, 0.0f), ih = fmaxf(rby - lty, 0.0f);
    float inter = iw * ih;
    float uni = a1 + a2 - inter;
    float iou = inter / (uni + 1e-6f);
    float ex0 = fminf(ax0, cx0), ey0 = fminf(ay0, cy0);
    float ex1 = fmaxf(ax1, cx1), ey1 = fmaxf(ey1 > ey1 ? ey1 : ay1, cy1); // placeholder removed below
    return 0.0f;
}

// NOTE: giou rewritten cleanly below (the above stub is unused).
__device__ __forceinline__ float giou2_f(const float* b, float lx, float ly, float lw, float lh) {
    float b1x0 = b[0] - b[2] * 0.5f, b1y0 = b[1] - b[3] * 0.5f;
    float b1x1 = b[0] + b[2] * 0.5f, b1y1 = b[1] + b[3] * 0.5f;
    float b2x0 = lx - lw * 0.5f, b2y0 = ly - lh * 0.5f;
    float b2x1 = lx + lw * 0.5f, b2y1 = ly + lh * 0.5f;
    float ax0 = fminf(b1x0, b1x1), ay0 = fminf(b1y0, b1y1);
    float ax1 = fmaxf(b1x0, b1x1), ay1 = fmaxf(b1y0, b1y1);
    float cx0 = fminf(b2x0, b2x1), cy0 = fminf(b2y0, b2y1);
    float cx1 = fmaxf(b2x0, b2x1), cy1 = fmaxf(b2y0, b2y1);
    float a1 = (ax1 - ax0) * (ay1 - ay0);
    float a2 = (cx1 - cx0) * (cy1 - cy0);
    float ltx = fmaxf(ax0, cx0), lty = fmaxf(ay0, cy0);
    float rbx = fminf(ax1, cx1), rby = fminf(ay1, cy1);
    float iw = fmaxf(rbx - ltx, 0.0f), ih = fmaxf(rby - lty, 0.0f);
    float inter = iw * ih;
    float uni = a1 + a2 - inter;
    float iou = inter / (uni + 1e-6f);
    float ex0 = fminf(ax0, cx0), ey0 = fminf(ay0, cy0);
    float ex1 = fmaxf(ax1, cx1), ey1 = fmaxf(ay1, cy1);
    float ew = fmaxf(ex1 - ex0, 0.0f), eh = fmaxf(ey1 - ey0, 0.0f);
    float enc = ew * eh;
    return iou - (enc - uni) / (enc + 1e-6f);
}

__device__ __forceinline__ void stage4(const float* __restrict__ g, float* __restrict__ s,
                                       int nv4, int tid) {
    const float4* gv = (const float4*)g;
    float4* sv = (float4*)s;
    for (int k = tid; k < nv4; k += 256) sv[k] = gv[k];
}

__global__ __launch_bounds__(256) void loss_all(Params P) {
    __shared__ __align__(16) float sbuf[7936];   // 31744 B: max slice (label, 256*31)
    __shared__ float red[4][16];

    int tid = threadIdx.x;
    int bid = blockIdx.x;
    int lvl, lblk, shift;
    float invStride;
    if (bid >= 1280)      { lvl = 2; lblk = bid - 1280; shift = 10; invStride = 1.0f / 32.0f; }
    else if (bid >= 1024) { lvl = 1; lblk = bid - 1024; shift = 12; invStride = 1.0f / 16.0f; }
    else                  { lvl = 0; lblk = bid;        shift = 14; invStride = 1.0f / 8.0f;  }
    int cell0 = lblk << 8;
    int c = cell0 + tid;
    int batch = c >> shift;   // uniform across block (G*G multiple of 256)

    // issue the lone uncoalesced load early (full p1 array is line-touched anyway)
    float conf1 = P.p1[lvl][(size_t)c * 10 + 9];

    // ---------------- stage label, extract per-cell label state ----------------
    stage4(P.lb[lvl] + (size_t)cell0 * 31, sbuf, 1984, tid);
    __syncthreads();
    const float* L = sbuf + tid * 31;
    float lx = L[0], ly = L[1], lw = L[2], lh = L[3];
    float l1234[4] = {L[4], L[5], L[6], L[7]};
    float la[4] = {L[8], L[9], L[10], L[11]};
    float lr = L[12];
    float flag = L[13];
    float mix = L[14];
    float area = L[15];
    float gh = 0.0f;
    unsigned nzm = 0u;
#pragma unroll
    for (int k = 0; k < NC; ++k) {
        float cv = L[16 + k];
        gh = fmaxf(gh, cv);
        if (cv != 0.0f) nzm |= (1u << k);
    }
    __syncthreads();

    float obj   = (flag == 1.0f) ? 1.0f : 0.0f;
    float noobj = (flag == 0.0f) ? 1.0f : 0.0f;
    float fuzzy = 1.0f - obj - noobj;
    float conf_t = obj * 0.99f + 0.005f;
    float aw = area + ((area == 0.0f) ? 1.0f : 0.0f);
    float bls = 2.0f - lw * lh * (1.0f / (1024.0f * 1024.0f));

    float v[16];
#pragma unroll
    for (int t = 0; t < 16; ++t) v[t] = 0.0f;
    v[15] = obj;   // per-batch obj count term

    // ---------------- head 1 (needs p1d + conf1) ----------------
    stage4(P.p1d[lvl] + (size_t)cell0 * 13, sbuf, 832, tid);
    __syncthreads();
    float pd[13];
#pragma unroll
    for (int k = 0; k < 13; ++k) pd[k] = sbuf[tid * 13 + k];
    __syncthreads();
    {
        float xiou = giou2_f(pd, lx, ly, lw, lh);
        float siou = bls * (1.0f - fminf(fmaxf(xiou, 0.0f), 1.0f));
        float sobb = 0.0f;
#pragma unroll
        for (int k = 0; k < 4; ++k) { float d = pd[4 + k] - la[k]; sobb += d * d; }
        float dr = pd[8] - lr;
        float sarea = dr * dr;
        float off = expf(-(siou + sobb + sarea));
        float g = (gh + off) * 0.5f;
        float bg = noobj + fuzzy * ((g < 0.3f) ? 1.0f : 0.0f) * (1.0f - fuzzy * g);
        float fg = obj * ((g >= 0.3f) ? 1.0f : 0.0f);
        float foc = focal_f(conf1, conf_t);
        float fma_ = fg * mix * aw;
        v[0] = fg * foc * mix * g;
        v[1] = bg * foc * mix;
        v[2] = fma_ * siou;
        v[3] = fma_ * sobb;
        v[4] = fma_ * sarea;
        float sl = 0.0f;
#pragma unroll
        for (int k = 0; k < 4; ++k) sl += sl1_f(pd[9 + k] * invStride, l1234[k] * invStride);
        v[5] = fg * bls * sl * mix * aw;
    }

    // ---------------- head 2 geometry (p2d) ----------------
    stage4(P.p2d[lvl] + (size_t)cell0 * 13, sbuf, 832, tid);
    __syncthreads();
#pragma unroll
    for (int k = 0; k < 13; ++k) pd[k] = sbuf[tid * 13 + k];
    __syncthreads();
    float siou2, sobb2, sarea2, off2, sl2;
    {
        float xiou = giou2_f(pd, lx, ly, lw, lh);
        siou2 = bls * (1.0f - fminf(fmaxf(xiou, 0.0f), 1.0f));
        sobb2 = 0.0f;
#pragma unroll
        for (int k = 0; k < 4; ++k) { float d = pd[4 + k] - la[k]; sobb2 += d * d; }
        float dr = pd[8] - lr;
        sarea2 = dr * dr;
        off2 = expf(-(siou2 + sobb2 + sarea2));
        sl2 = 0.0f;
#pragma unroll
        for (int k = 0; k < 4; ++k) sl2 += sl1_f(pd[9 + k] * invStride, l1234[k] * invStride);
    }

    // ---------------- head 2 conf + classes (p2) ----------------
    stage4(P.p2[lvl] + (size_t)cell0 * 25, sbuf, 1600, tid);
    __syncthreads();
    {
        const float* Q = sbuf + tid * 25;
        float conf2 = Q[9];
        float g = (gh + off2) * 0.5f;
        float bg = noobj + fuzzy * ((g < 0.3f) ? 1.0f : 0.0f) * (1.0f - fuzzy * g);
        float fg = obj * ((g >= 0.3f) ? 1.0f : 0.0f);
        float foc = focal_f(conf2, conf_t);
        v[6] = fg * foc * mix * g;
        v[7] = bg * foc * mix;

        float pos = 0.0f, neg = 0.0f, wsum = 0.0f, clsb = 0.0f;
#pragma unroll
        for (int k = 0; k < NC; ++k) {
            float x = Q[10 + k];
            bool nz = (nzm >> k) & 1u;
            float smn = (nz ? 0.99f : 0.0f) + (0.01f / 15.0f);
            float b0 = bce_f(x, smn);
            clsb += b0;
            if (nz) {
                pos += bce_f(x, smn * off2);
                wsum += sig_f(x);
            } else {
                neg += b0;
            }
        }
        float wgq = (wsum + gh) * 0.5f;
        float oma = obj * mix * aw;
        v[8] = oma * pos;
        v[9] = oma * neg;
        float fmaw = fg * mix * aw * wgq;
        v[10] = fmaw * siou2;
        v[12] = fmaw * sobb2;
        v[13] = fmaw * sarea2;
        v[14] = fg * bls * sl2 * mix * aw * wgq;
        v[11] = fg * clsb * mix * aw;
    }

    // ---------------- block reduction -> per-(level,batch) double atomics ----------------
    int lane = tid & 63;
    int wid = tid >> 6;
#pragma unroll
    for (int t = 0; t < 16; ++t) {
        float x = v[t];
#pragma unroll
        for (int o = 32; o > 0; o >>= 1) x += __shfl_down(x, o);
        if (lane == 0) red[wid][t] = x;
    }
    __syncthreads();
    if (tid < 16) {
        float total = red[0][tid] + red[1][tid] + red[2][tid] + red[3][tid];
        atomicAdd(&P.sums[((size_t)lvl * 16 + batch) * 16 + tid], (double)total);
    }
}

__global__ void finalize_kernel(const double* __restrict__ S, float* __restrict__ out) {
    if (threadIdx.x == 0 && blockIdx.x == 0) {
        double tot[15];
#pragma unroll
        for (int t = 0; t < 15; ++t) tot[t] = 0.0;
        for (int lb = 0; lb < 48; ++lb) {
            const double* s = S + (size_t)lb * 16;
            double invN = 1.0 / fmax(s[15], 1.0);
            for (int t = 0; t < 15; ++t) tot[t] += s[t] * invN;
        }
        const double invB = 1.0 / 16.0;
        double fg  = (tot[0] + tot[6]) * invB;
        double bg  = (tot[1] + tot[7]) * invB;
        double pos = tot[8]  * invB * 28.0;   // *(NC-1)=14, then *2
        double neg = tot[9]  * invB * 2.0;
        double cls = tot[11] * invB;
        double iou = (tot[2] + tot[10]) * invB * 0.5;
        double s_  = (tot[3] + tot[12]) * invB * 0.5;
        double r   = (tot[4] + tot[13]) * invB * 8.0;    // 16 * avg-of-2
        double l   = (tot[5] + tot[14]) * invB * 0.1;    // 0.2 * avg-of-2
        double loss = fg + bg + iou + s_ + r + pos + neg + l;
        out[0] = (float)loss; out[1] = (float)fg; out[2] = (float)bg;
        out[3] = (float)pos;  out[4] = (float)neg; out[5] = (float)iou;
        out[6] = (float)cls;  out[7] = (float)s_;  out[8] = (float)r;
        out[9] = (float)l;
    }
}

extern "C" void kernel_launch(void* const* d_in, const int* in_sizes, int n_in,
                              void* d_out, int out_size, void* d_ws, size_t ws_size,
                              hipStream_t stream) {
    (void)in_sizes; (void)n_in; (void)out_size; (void)ws_size;
    double* sums = (double*)d_ws;   // 3*16*16 doubles = 6144 B
    hipMemsetAsync(d_ws, 0, 3 * 16 * 16 * sizeof(double), stream);

    Params P;
    for (int lvl = 0; lvl < 3; ++lvl) {
        P.p1[lvl]  = (const float*)d_in[lvl * 5 + 0];
        P.p1d[lvl] = (const float*)d_in[lvl * 5 + 1];
        P.p2[lvl]  = (const float*)d_in[lvl * 5 + 2];
        P.p2d[lvl] = (const float*)d_in[lvl * 5 + 3];
        P.lb[lvl]  = (const float*)d_in[lvl * 5 + 4];
    }
    P.sums = sums;

    loss_all<<<dim3(1344), dim3(256), 0, stream>>>(P);
    finalize_kernel<<<dim3(1), dim3(64), 0, stream>>>(sums, (float*)d_out);
}